// Round 7
// baseline (264.228 us; speedup 1.0000x reference)
//
#include <hip/hip_runtime.h>

typedef __attribute__((ext_vector_type(8))) short  short8;
typedef __attribute__((ext_vector_type(4))) float  floatx4;
typedef __attribute__((ext_vector_type(4))) int    intx4;

constexpr int DIN = 100;
constexpr int H   = 64;
constexpr int G   = 10;
constexpr int NH  = 5;
constexpr int MWG = 128;                 // rows per tile (4 waves x 32 rows)
constexpr int TPB = 4;                   // tiles per block (grid = B/MWG/TPB = 512)
constexpr int HP  = 72;                  // hbuf pitch in halfwords: 144B rows, 16B-aligned
constexpr int PBP = 20;                  // pbuf pitch (floats): 16 payload + 4 pad
                                         // (density writes floatx4 at 4q, q=0..3 -> needs 16!)

// fragment counts in ws: dW0 (K=128 padded) 16; dW1 8; dbW 2; W0 5h*8=40
constexpr int NF_DW0 = 16, NF_DW1 = 8, NF_DBW = 2;
constexpr int NF_LIN = NF_DW0 + NF_DW1 + NF_DBW;     // 26
constexpr int NF_TOT = NF_LIN + 40;                  // 66

__device__ __forceinline__ unsigned short f2bf_rne(float f) {
    union { float f; unsigned u; } v{f};
    unsigned r = v.u + 0x7FFF + ((v.u >> 16) & 1);   // RNE
    return (unsigned short)(r >> 16);
}

// round-half-up pack of 8 floats -> short8 (bf16)
__device__ __forceinline__ short8 pack8(const float* f) {
    intx4 p;
    #pragma unroll
    for (int j = 0; j < 4; ++j) {
        unsigned a = __float_as_uint(f[2 * j])     + 0x8000u;
        unsigned b = __float_as_uint(f[2 * j + 1]) + 0x8000u;
        p[j] = (int)((b & 0xFFFF0000u) | (a >> 16));
    }
    union { intx4 i; short8 s; } u; u.i = p;
    return u.s;
}

// round-half-up pack of 2 floats -> one dword of 2 bf16 (same rounding as above)
__device__ __forceinline__ unsigned pack2bf(float a, float b) {
    unsigned ua = __float_as_uint(a) + 0x8000u;
    unsigned ub = __float_as_uint(b) + 0x8000u;
    return (ua >> 16) | (ub & 0xFFFF0000u);
}

__device__ __forceinline__ short8 ldfrag(const unsigned short* __restrict__ ws,
                                         int f, int lane) {
    return *(const short8*)(ws + (size_t)(f * 64 + lane) * 8);
}

// lgkm-only barrier: does NOT drain vmcnt, so prefetched global loads stay
// in flight across it (plain __syncthreads drains vmcnt(0) and would stall).
// All cross-wave communication in this kernel is through LDS (lgkm-counted).
__device__ __forceinline__ void bar_lgkm() {
    asm volatile("s_waitcnt lgkmcnt(0)" ::: "memory");
    __builtin_amdgcn_s_barrier();
    asm volatile("" ::: "memory");
}

// ---- pre-kernel: pack all weights as bf16 MFMA fragments into ws ----
// Layout note: lane holds W[k = (lane>>4)*8 + j][n = lane&15]. This is
// simultaneously the B-fragment of W and the A-fragment of W^T — the main
// kernel uses them as A-operands to compute transposed outputs h^T.
__global__ __launch_bounds__(64) void pack_kernel(
    const float* __restrict__ dW0, const float* __restrict__ dW1,
    const float* __restrict__ dbW, const float* __restrict__ W0,
    unsigned short* __restrict__ ws)
{
    const int f = blockIdx.x;            // fragment id 0..65
    const int lane = threadIdx.x;
    const int q = lane >> 4, cl = lane & 15;
    float v[8];
    if (f < NF_DW0) {                    // dW0: K padded 100->128 with zeros
        int c = f >> 2, g = f & 3;
        #pragma unroll
        for (int j = 0; j < 8; ++j) {
            int k = c * 32 + q * 8 + j, n = g * 16 + cl;
            v[j] = (k < DIN) ? dW0[k * H + n] : 0.0f;
        }
    } else if (f < NF_DW0 + NF_DW1) {    // dW1: K=64
        int r = f - NF_DW0; int c = r >> 2, g = r & 3;
        #pragma unroll
        for (int j = 0; j < 8; ++j) {
            int k = c * 32 + q * 8 + j, n = g * 16 + cl;
            v[j] = dW1[k * H + n];
        }
    } else if (f < NF_LIN) {             // dbW: K=64, N=11 padded to 16
        int c = f - (NF_DW0 + NF_DW1);
        #pragma unroll
        for (int j = 0; j < 8; ++j) {
            int k = c * 32 + q * 8 + j, n = cl;
            v[j] = (n <= G) ? dbW[k * (G + 1) + n] : 0.0f;
        }
    } else {                             // W0: 5 heads, K=64
        int r = f - NF_LIN; int h = r >> 3; r &= 7; int c = r >> 2, g = r & 3;
        #pragma unroll
        for (int j = 0; j < 8; ++j) {
            int k = c * 32 + q * 8 + j, n = g * 16 + cl;
            v[j] = W0[(h * H + k) * H + n];
        }
    }
    short8 s;
    #pragma unroll
    for (int j = 0; j < 8; ++j) s[j] = (short)f2bf_rne(v[j]);
    *(short8*)(ws + (size_t)(f * 64 + lane) * 8) = s;
}

// ---- main kernel (operand-swapped MFMAs: D = W^T @ x^T = h^T) ----
// Each block loops over TPB consecutive 128-row tiles: weights/params stay
// L1/L2-hot across iterations; the NEXT tile's x loads are issued at the
// start of the heads phase so their HBM latency hides under head compute.
__global__ __launch_bounds__(256, 3) void drnet_mfma(
    const float* __restrict__ dosage, const float* __restrict__ x,
    const float* __restrict__ db0, const float* __restrict__ db1,
    const float* __restrict__ dbB,
    const float* __restrict__ tw0, const float* __restrict__ b0,
    const float* __restrict__ W1, const float* __restrict__ tw1,
    const float* __restrict__ b1,
    const unsigned short* __restrict__ wsfrag,
    float* __restrict__ outg, float* __restrict__ outq)
{
    __shared__ unsigned short hbuf[MWG * HP];    // 18432 B
    __shared__ float          pbuf[4][16][PBP];  // 5120 B: wave-private softmax scratch
    __shared__ int            perm[MWG];         // sorted pos -> row-in-tile
    __shared__ float          tbuf[MWG];         // dosage in sorted order
    __shared__ unsigned char  bkbuf[MWG];        // bucket in sorted order
    __shared__ float          qbuf[MWG];         // Q in original row order
    __shared__ int            hist[NH];
    __shared__ int            offs[NH];

    const int tid  = threadIdx.x;
    const int wave = tid >> 6, lane = tid & 63;
    const int q = lane >> 4, cl = lane & 15;
    unsigned short* hb = hbuf + wave * 32 * HP;

    const int tilebase = blockIdx.x * TPB;       // contiguous chunk of tiles

    // ======= prefetch tile 0's dosage + x =======
    floatx4 tvs[2];
    floatx4 xv[2][7];
    {
        const int rowbase = tilebase * MWG + wave * 32;
        #pragma unroll
        for (int mt = 0; mt < 2; ++mt)
            tvs[mt] = *(const floatx4*)(dosage + rowbase + mt * 16 + 4 * q);
        #pragma unroll
        for (int mt = 0; mt < 2; ++mt) {
            const float* xr = x + (size_t)(rowbase + mt * 16 + cl) * DIN;
            #pragma unroll
            for (int cch = 0; cch < 3; ++cch) {
                xv[mt][2 * cch]     = *(const floatx4*)(xr + cch * 32 + q * 8);
                xv[mt][2 * cch + 1] = *(const floatx4*)(xr + cch * 32 + q * 8 + 4);
            }
            xv[mt][6] = (q == 0) ? *(const floatx4*)(xr + 96) : (floatx4)0.0f;
        }
    }

    #pragma unroll 1
    for (int t = 0; t < TPB; ++t) {
        const int rowbase = (tilebase + t) * MWG + wave * 32;

        // ============== phase 0: counting sort by dosage bucket ==============
        if (tid < NH) hist[tid] = 0;
        bar_lgkm();
        {
            float t8[2][4];
            int   bk8[2][4];
            #pragma unroll
            for (int mt = 0; mt < 2; ++mt)
                #pragma unroll
                for (int r = 0; r < 4; ++r) {
                    float tt = tvs[mt][r];
                    t8[mt][r] = tt;
                    int bk = (int)floorf(tt * (float)NH);
                    bk8[mt][r] = min(max(bk, 0), NH - 1);
                }
            if (cl == 0) {
                #pragma unroll
                for (int mt = 0; mt < 2; ++mt)
                    #pragma unroll
                    for (int r = 0; r < 4; ++r)
                        atomicAdd(&hist[bk8[mt][r]], 1);
            }
            bar_lgkm();
            if (tid == 0) {
                int a = 0;
                #pragma unroll
                for (int h = 0; h < NH; ++h) { offs[h] = a; a += hist[h]; }
            }
            bar_lgkm();
            if (cl == 0) {
                #pragma unroll
                for (int mt = 0; mt < 2; ++mt)
                    #pragma unroll
                    for (int r = 0; r < 4; ++r) {
                        const int bk  = bk8[mt][r];
                        const int pos = atomicAdd(&offs[bk], 1);
                        perm[pos]  = wave * 32 + mt * 16 + 4 * q + r;
                        tbuf[pos]  = t8[mt][r];
                        bkbuf[pos] = (unsigned char)bk;
                    }
            }
            // perm/tbuf/bkbuf visibility guaranteed by the pre-heads barrier
        }

        // ====== layer 1: h1^T = dW0^T @ x^T, both mt merged (8 acc chains) ======
        {
            short8 a1[2][4];
            #pragma unroll
            for (int mt = 0; mt < 2; ++mt)
                #pragma unroll
                for (int cch = 0; cch < 4; ++cch) {
                    float f[8];
                    if (cch < 3) {
                        #pragma unroll
                        for (int j = 0; j < 4; ++j) {
                            f[j]     = xv[mt][2 * cch][j];
                            f[4 + j] = xv[mt][2 * cch + 1][j];
                        }
                    } else {
                        #pragma unroll
                        for (int j = 0; j < 4; ++j) {
                            f[j]     = xv[mt][6][j];
                            f[4 + j] = 0.0f;
                        }
                    }
                    a1[mt][cch] = pack8(f);
                }
            floatx4 acc[2][4];
            #pragma unroll
            for (int mt = 0; mt < 2; ++mt)
                #pragma unroll
                for (int g = 0; g < 4; ++g) acc[mt][g] = (floatx4)0.0f;
            #pragma unroll
            for (int cch = 0; cch < 4; ++cch)
                #pragma unroll
                for (int g = 0; g < 4; ++g) {
                    short8 bf = ldfrag(wsfrag, cch * 4 + g, lane);  // shared by both mt
                    acc[0][g] = __builtin_amdgcn_mfma_f32_16x16x32_bf16(bf, a1[0][cch], acc[0][g], 0, 0, 0);
                    acc[1][g] = __builtin_amdgcn_mfma_f32_16x16x32_bf16(bf, a1[1][cch], acc[1][g], 0, 0, 0);
                }
            #pragma unroll
            for (int mt = 0; mt < 2; ++mt)
                #pragma unroll
                for (int g = 0; g < 4; ++g) {
                    floatx4 bias = *(const floatx4*)(db0 + g * 16 + 4 * q);
                    float v0 = fmaxf(acc[mt][g][0] + bias[0], 0.0f);
                    float v1 = fmaxf(acc[mt][g][1] + bias[1], 0.0f);
                    float v2 = fmaxf(acc[mt][g][2] + bias[2], 0.0f);
                    float v3 = fmaxf(acc[mt][g][3] + bias[3], 0.0f);
                    *(uint2*)(hb + (size_t)(mt * 16 + cl) * HP + g * 16 + 4 * q) =
                        make_uint2(pack2bf(v0, v1), pack2bf(v2, v3));
                }
        }
        // wave-private rows + in-order DS pipe: no barrier needed

        // ====== layer 2: h2^T = dW1^T @ h1^T, both mt merged ======
        {
            short8 a2[2][2];
            #pragma unroll
            for (int mt = 0; mt < 2; ++mt)
                #pragma unroll
                for (int cch = 0; cch < 2; ++cch)
                    a2[mt][cch] = *(const short8*)(hb + (mt * 16 + cl) * HP + cch * 32 + q * 8);
            floatx4 acc[2][4];
            #pragma unroll
            for (int mt = 0; mt < 2; ++mt)
                #pragma unroll
                for (int g = 0; g < 4; ++g) acc[mt][g] = (floatx4)0.0f;
            #pragma unroll
            for (int cch = 0; cch < 2; ++cch)
                #pragma unroll
                for (int g = 0; g < 4; ++g) {
                    short8 bf = ldfrag(wsfrag, NF_DW0 + cch * 4 + g, lane);
                    acc[0][g] = __builtin_amdgcn_mfma_f32_16x16x32_bf16(bf, a2[0][cch], acc[0][g], 0, 0, 0);
                    acc[1][g] = __builtin_amdgcn_mfma_f32_16x16x32_bf16(bf, a2[1][cch], acc[1][g], 0, 0, 0);
                }
            #pragma unroll
            for (int mt = 0; mt < 2; ++mt)
                #pragma unroll
                for (int g = 0; g < 4; ++g) {
                    floatx4 bias = *(const floatx4*)(db1 + g * 16 + 4 * q);
                    float v0 = fmaxf(acc[mt][g][0] + bias[0], 0.0f);
                    float v1 = fmaxf(acc[mt][g][1] + bias[1], 0.0f);
                    float v2 = fmaxf(acc[mt][g][2] + bias[2], 0.0f);
                    float v3 = fmaxf(acc[mt][g][3] + bias[3], 0.0f);
                    *(uint2*)(hb + (size_t)(mt * 16 + cl) * HP + g * 16 + 4 * q) =
                        make_uint2(pack2bf(v0, v1), pack2bf(v2, v3));
                }
        }

        // ====== density: p^T = softmax(dbW^T @ h2^T + dbB) + interp ======
        // thread holds logits for grid dims 4q+r of batch row cl
        {
            float tden[2];
            #pragma unroll
            for (int mt = 0; mt < 2; ++mt)
                tden[mt] = dosage[rowbase + mt * 16 + cl];
            short8 af[2][2];
            #pragma unroll
            for (int mt = 0; mt < 2; ++mt)
                #pragma unroll
                for (int cch = 0; cch < 2; ++cch)
                    af[mt][cch] = *(const short8*)(hb + (mt * 16 + cl) * HP + cch * 32 + q * 8);
            floatx4 accd[2];
            accd[0] = (floatx4)0.0f; accd[1] = (floatx4)0.0f;
            #pragma unroll
            for (int cch = 0; cch < 2; ++cch) {
                short8 bf = ldfrag(wsfrag, NF_DW0 + NF_DW1 + cch, lane);
                #pragma unroll
                for (int mt = 0; mt < 2; ++mt)
                    accd[mt] = __builtin_amdgcn_mfma_f32_16x16x32_bf16(bf, af[mt][cch], accd[mt], 0, 0, 0);
            }
            #pragma unroll
            for (int mt = 0; mt < 2; ++mt) {
                floatx4 ev;
                float sp = 0.0f;
                #pragma unroll
                for (int r = 0; r < 4; ++r) {
                    const int gd = 4 * q + r;
                    float e = (gd <= G) ? __expf(accd[mt][r] + dbB[gd]) : 0.0f;
                    ev[r] = e;
                    sp += e;
                }
                float s = sp;
                s += __shfl_xor(s, 16); s += __shfl_xor(s, 32);   // sum over grid dims
                *(floatx4*)(&pbuf[wave][cl][4 * q]) = ev;         // exchange across q
                const float tt = tden[mt];
                const float tB = tt * (float)G;
                const float U  = ceilf(tB);
                const float inter = 1.0f - (U - tB);
                int Ui = (int)U; int Li = Ui - 1; if (Li < 0) Li = 0;
                const float pL = pbuf[wave][cl][Li];
                const float pU = pbuf[wave][cl][Ui];
                if (q == 0)
                    outg[rowbase + mt * 16 + cl] = (pL + (pU - pL) * inter) / s;
            }
        }

        // ====== heads: h0^T = W0^T @ h2^T on sorted tiles; per-thread bucket ======
        bar_lgkm();      // all h2 in hbuf + perm/tbuf/bkbuf visible (LDS-only)

        // issue NEXT tile's x/dosage loads: latency hides under head compute
        if (t + 1 < TPB) {
            const int rbn = rowbase + MWG;
            #pragma unroll
            for (int mt = 0; mt < 2; ++mt)
                tvs[mt] = *(const floatx4*)(dosage + rbn + mt * 16 + 4 * q);
            #pragma unroll
            for (int mt = 0; mt < 2; ++mt) {
                const float* xr = x + (size_t)(rbn + mt * 16 + cl) * DIN;
                #pragma unroll
                for (int cch = 0; cch < 3; ++cch) {
                    xv[mt][2 * cch]     = *(const floatx4*)(xr + cch * 32 + q * 8);
                    xv[mt][2 * cch + 1] = *(const floatx4*)(xr + cch * 32 + q * 8 + 4);
                }
                xv[mt][6] = (q == 0) ? *(const floatx4*)(xr + 96) : (floatx4)0.0f;
            }
        }

        {
            short8 ag[2][2];
            int    prow[2], bkme[2], blo[2], bhi[2];
            float  tme[2];
            #pragma unroll
            for (int mt = 0; mt < 2; ++mt) {
                const int base = (wave * 2 + mt) * 16;   // my sorted 16-row tile
                prow[mt] = perm[base + cl];              // thread's batch row = cl
                ag[mt][0] = *(const short8*)(hbuf + prow[mt] * HP + q * 8);
                ag[mt][1] = *(const short8*)(hbuf + prow[mt] * HP + 32 + q * 8);
                tme[mt]  = tbuf[base + cl];
                bkme[mt] = bkbuf[base + cl];
                blo[mt]  = bkbuf[base];
                bhi[mt]  = bkbuf[base + 15];             // contiguous bucket range
            }
            #pragma unroll
            for (int mt = 0; mt < 2; ++mt) {
                float qp = 0.0f;
                #pragma unroll 1
                for (int h = blo[mt]; h <= bhi[mt]; ++h) {
                    floatx4 acch[4];
                    #pragma unroll
                    for (int g = 0; g < 4; ++g) acch[g] = (floatx4)0.0f;
                    #pragma unroll
                    for (int cch = 0; cch < 2; ++cch)
                        #pragma unroll
                        for (int g = 0; g < 4; ++g) {
                            short8 bf = ldfrag(wsfrag, NF_LIN + h * 8 + cch * 4 + g, lane);
                            acch[g] = __builtin_amdgcn_mfma_f32_16x16x32_bf16(bf, ag[mt][cch], acch[g], 0, 0, 0);
                        }
                    if (bkme[mt] == h) { // exec-masked: total epilogue ~= one pass
                        #pragma unroll
                        for (int g = 0; g < 4; ++g) {
                            const int off = h * H + g * 16 + 4 * q;
                            floatx4 tw0v = *(const floatx4*)(tw0 + off);
                            floatx4 b0v  = *(const floatx4*)(b0  + off);
                            floatx4 w1v  = *(const floatx4*)(W1  + off);
                            #pragma unroll
                            for (int r = 0; r < 4; ++r)
                                qp += fmaxf(acch[g][r] + tme[mt] * tw0v[r] + b0v[r], 0.0f) * w1v[r];
                        }
                    }
                }
                qp += __shfl_xor(qp, 16); qp += __shfl_xor(qp, 32);   // sum over hid
                if (q == 0)
                    qbuf[prow[mt]] = qp + tme[mt] * tw1[bkme[mt]] + b1[bkme[mt]];
            }
        }

        // coalesced Q store (qbuf is in original row order)
        bar_lgkm();
        if (tid < MWG / 4) {
            floatx4 v = *(const floatx4*)(qbuf + tid * 4);
            *(floatx4*)(outq + (tilebase + t) * MWG + tid * 4) = v;
        }
    }
}

extern "C" void kernel_launch(void* const* d_in, const int* in_sizes, int n_in,
                              void* d_out, int out_size, void* d_ws, size_t ws_size,
                              hipStream_t stream) {
    const float* dosage = (const float*)d_in[0];
    const float* x      = (const float*)d_in[1];
    const float* dW0    = (const float*)d_in[2];
    const float* db0    = (const float*)d_in[3];
    const float* dW1    = (const float*)d_in[4];
    const float* db1    = (const float*)d_in[5];
    const float* dbW    = (const float*)d_in[6];
    const float* dbB    = (const float*)d_in[7];
    const float* W0     = (const float*)d_in[8];
    const float* tw0    = (const float*)d_in[9];
    const float* b0     = (const float*)d_in[10];
    const float* W1     = (const float*)d_in[11];
    const float* tw1    = (const float*)d_in[12];
    const float* b1     = (const float*)d_in[13];

    const int Btot = in_sizes[0];
    float* outg = (float*)d_out;
    float* outq = outg + Btot;
    unsigned short* ws = (unsigned short*)d_ws;

    pack_kernel<<<NF_TOT, 64, 0, stream>>>(dW0, dW1, dbW, W0, ws);
    drnet_mfma<<<Btot / (MWG * TPB), 256, 0, stream>>>(dosage, x, db0, db1, dbB,
                                                       tw0, b0, W1, tw1, b1,
                                                       ws, outg, outq);
}

// Round 8
// 227.986 us; speedup vs baseline: 1.1590x; 1.1590x over previous
//
#include <hip/hip_runtime.h>

typedef __attribute__((ext_vector_type(8))) short  short8;
typedef __attribute__((ext_vector_type(4))) float  floatx4;
typedef __attribute__((ext_vector_type(4))) int    intx4;

constexpr int DIN = 100;
constexpr int H   = 64;
constexpr int G   = 10;
constexpr int NH  = 5;
constexpr int MWG = 128;                 // rows per block (4 waves x 32 rows)
constexpr int HP  = 72;                  // hbuf pitch in halfwords: 144B rows, 16B-aligned
constexpr int PBP = 20;                  // pbuf pitch (floats): 16 payload + 4 pad

// fragment counts in ws: dW0 (K=128 padded) 16; dW1 8; dbW 2; W0 5h*8=40
constexpr int NF_DW0 = 16, NF_DW1 = 8, NF_DBW = 2;
constexpr int NF_LIN = NF_DW0 + NF_DW1 + NF_DBW;     // 26
constexpr int NF_TOT = NF_LIN + 40;                  // 66

__device__ __forceinline__ unsigned short f2bf_rne(float f) {
    union { float f; unsigned u; } v{f};
    unsigned r = v.u + 0x7FFF + ((v.u >> 16) & 1);   // RNE
    return (unsigned short)(r >> 16);
}

// round-half-up pack of 8 floats -> short8 (bf16)
__device__ __forceinline__ short8 pack8(const float* f) {
    intx4 p;
    #pragma unroll
    for (int j = 0; j < 4; ++j) {
        unsigned a = __float_as_uint(f[2 * j])     + 0x8000u;
        unsigned b = __float_as_uint(f[2 * j + 1]) + 0x8000u;
        p[j] = (int)((b & 0xFFFF0000u) | (a >> 16));
    }
    union { intx4 i; short8 s; } u; u.i = p;
    return u.s;
}

// round-half-up pack of 2 floats -> one dword of 2 bf16 (same rounding as above)
__device__ __forceinline__ unsigned pack2bf(float a, float b) {
    unsigned ua = __float_as_uint(a) + 0x8000u;
    unsigned ub = __float_as_uint(b) + 0x8000u;
    return (ua >> 16) | (ub & 0xFFFF0000u);
}

__device__ __forceinline__ short8 ldfrag(const unsigned short* __restrict__ ws,
                                         int f, int lane) {
    return *(const short8*)(ws + (size_t)(f * 64 + lane) * 8);
}

// ---- pre-kernel: pack all weights as bf16 MFMA fragments into ws ----
// Layout note: lane holds W[k = (lane>>4)*8 + j][n = lane&15]. This is
// simultaneously the B-fragment of W and the A-fragment of W^T — the main
// kernel uses them as A-operands to compute transposed outputs h^T.
__global__ __launch_bounds__(64) void pack_kernel(
    const float* __restrict__ dW0, const float* __restrict__ dW1,
    const float* __restrict__ dbW, const float* __restrict__ W0,
    unsigned short* __restrict__ ws)
{
    const int f = blockIdx.x;            // fragment id 0..65
    const int lane = threadIdx.x;
    const int q = lane >> 4, cl = lane & 15;
    float v[8];
    if (f < NF_DW0) {                    // dW0: K padded 100->128 with zeros
        int c = f >> 2, g = f & 3;
        #pragma unroll
        for (int j = 0; j < 8; ++j) {
            int k = c * 32 + q * 8 + j, n = g * 16 + cl;
            v[j] = (k < DIN) ? dW0[k * H + n] : 0.0f;
        }
    } else if (f < NF_DW0 + NF_DW1) {    // dW1: K=64
        int r = f - NF_DW0; int c = r >> 2, g = r & 3;
        #pragma unroll
        for (int j = 0; j < 8; ++j) {
            int k = c * 32 + q * 8 + j, n = g * 16 + cl;
            v[j] = dW1[k * H + n];
        }
    } else if (f < NF_LIN) {             // dbW: K=64, N=11 padded to 16
        int c = f - (NF_DW0 + NF_DW1);
        #pragma unroll
        for (int j = 0; j < 8; ++j) {
            int k = c * 32 + q * 8 + j, n = cl;
            v[j] = (n <= G) ? dbW[k * (G + 1) + n] : 0.0f;
        }
    } else {                             // W0: 5 heads, K=64
        int r = f - NF_LIN; int h = r >> 3; r &= 7; int c = r >> 2, g = r & 3;
        #pragma unroll
        for (int j = 0; j < 8; ++j) {
            int k = c * 32 + q * 8 + j, n = g * 16 + cl;
            v[j] = W0[(h * H + k) * H + n];
        }
    }
    short8 s;
    #pragma unroll
    for (int j = 0; j < 8; ++j) s[j] = (short)f2bf_rne(v[j]);
    *(short8*)(ws + (size_t)(f * 64 + lane) * 8) = s;
}

// ---- main kernel (operand-swapped MFMAs: D = W^T @ x^T = h^T) ----
// BARRIER-FREE: every phase is wave-private. Each wave owns 32 consecutive
// rows; the dosage-bucket sort is a wave-level ballot counting sort of those
// 32 rows; heads gather from the wave's own hbuf region. Cross-lane LDS
// communication within one wave relies on the in-order per-wave DS pipe
// (same pattern rounds 0-5 used for hbuf reuse). 6 blocks/CU allowed.
__global__ __launch_bounds__(256, 6) void drnet_mfma(
    const float* __restrict__ dosage, const float* __restrict__ x,
    const float* __restrict__ db0, const float* __restrict__ db1,
    const float* __restrict__ dbB,
    const float* __restrict__ tw0, const float* __restrict__ b0,
    const float* __restrict__ W1, const float* __restrict__ tw1,
    const float* __restrict__ b1,
    const unsigned short* __restrict__ wsfrag,
    float* __restrict__ outg, float* __restrict__ outq)
{
    __shared__ unsigned short hbuf[4][32 * HP];  // 18432 B (4608 B per wave)
    __shared__ float          pbuf[4][16][PBP];  //  5120 B: softmax scratch
    __shared__ int            perm[4][32];       //   512 B: sorted pos -> wave row
    __shared__ float          tbufs[4][32];      //   512 B: dosage, sorted order
    __shared__ int            bks[4][32];        //   512 B: bucket, sorted order
    __shared__ float          qbufs[4][32];      //   512 B: Q in wave row order

    const int tid  = threadIdx.x;
    const int wave = tid >> 6, lane = tid & 63;
    const int q = lane >> 4, cl = lane & 15;
    const int rowbase = blockIdx.x * MWG + wave * 32;   // this wave's 32 rows
    unsigned short* hb = hbuf[wave];

    // ======= prefetch this wave's x (liveness: top -> layer 1 only) =======
    floatx4 xv[2][7];
    #pragma unroll
    for (int mt = 0; mt < 2; ++mt) {
        const float* xr = x + (size_t)(rowbase + mt * 16 + cl) * DIN;
        #pragma unroll
        for (int cch = 0; cch < 3; ++cch) {
            xv[mt][2 * cch]     = *(const floatx4*)(xr + cch * 32 + q * 8);
            xv[mt][2 * cch + 1] = *(const floatx4*)(xr + cch * 32 + q * 8 + 4);
        }
        xv[mt][6] = (q == 0) ? *(const floatx4*)(xr + 96) : (floatx4)0.0f;
    }

    // ======= wave-private ballot counting sort of the wave's 32 rows =======
    // lanes 32-63 mirror lanes 0-31 (row = lane&31); ballots dedup'd by
    // truncating to the low 32 bits. Register-only: no atomics, no barriers.
    {
        const int row = lane & 31;
        const float tl = dosage[rowbase + row];
        int bk = (int)floorf(tl * (float)NH);
        bk = min(max(bk, 0), NH - 1);
        const unsigned m0 = (unsigned)__ballot(bk == 0);
        const unsigned m1 = (unsigned)__ballot(bk == 1);
        const unsigned m2 = (unsigned)__ballot(bk == 2);
        const unsigned m3 = (unsigned)__ballot(bk == 3);
        const unsigned m4 = (unsigned)__ballot(bk == 4);
        int base = 0;
        base += (bk > 0) ? __popc(m0) : 0;
        base += (bk > 1) ? __popc(m1) : 0;
        base += (bk > 2) ? __popc(m2) : 0;
        base += (bk > 3) ? __popc(m3) : 0;
        const unsigned mymask = (bk == 0) ? m0 : (bk == 1) ? m1 :
                                (bk == 2) ? m2 : (bk == 3) ? m3 : m4;
        const int pos = base + __popc(mymask & ((1u << row) - 1u));
        if (lane < 32) {                 // one writer per row
            perm[wave][pos]  = row;
            tbufs[wave][pos] = tl;
            bks[wave][pos]   = bk;
        }
    }

    // ====== layer 1: h1^T = dW0^T @ x^T, both mt merged (8 acc chains) ======
    {
        short8 a1[2][4];
        #pragma unroll
        for (int mt = 0; mt < 2; ++mt)
            #pragma unroll
            for (int cch = 0; cch < 4; ++cch) {
                float f[8];
                if (cch < 3) {
                    #pragma unroll
                    for (int j = 0; j < 4; ++j) {
                        f[j]     = xv[mt][2 * cch][j];
                        f[4 + j] = xv[mt][2 * cch + 1][j];
                    }
                } else {
                    #pragma unroll
                    for (int j = 0; j < 4; ++j) {
                        f[j]     = xv[mt][6][j];
                        f[4 + j] = 0.0f;
                    }
                }
                a1[mt][cch] = pack8(f);
            }
        floatx4 acc[2][4];
        #pragma unroll
        for (int mt = 0; mt < 2; ++mt)
            #pragma unroll
            for (int g = 0; g < 4; ++g) acc[mt][g] = (floatx4)0.0f;
        #pragma unroll
        for (int cch = 0; cch < 4; ++cch)
            #pragma unroll
            for (int g = 0; g < 4; ++g) {
                short8 bf = ldfrag(wsfrag, cch * 4 + g, lane);  // shared by both mt
                acc[0][g] = __builtin_amdgcn_mfma_f32_16x16x32_bf16(bf, a1[0][cch], acc[0][g], 0, 0, 0);
                acc[1][g] = __builtin_amdgcn_mfma_f32_16x16x32_bf16(bf, a1[1][cch], acc[1][g], 0, 0, 0);
            }
        #pragma unroll
        for (int mt = 0; mt < 2; ++mt)
            #pragma unroll
            for (int g = 0; g < 4; ++g) {
                floatx4 bias = *(const floatx4*)(db0 + g * 16 + 4 * q);
                float v0 = fmaxf(acc[mt][g][0] + bias[0], 0.0f);
                float v1 = fmaxf(acc[mt][g][1] + bias[1], 0.0f);
                float v2 = fmaxf(acc[mt][g][2] + bias[2], 0.0f);
                float v3 = fmaxf(acc[mt][g][3] + bias[3], 0.0f);
                *(uint2*)(hb + (size_t)(mt * 16 + cl) * HP + g * 16 + 4 * q) =
                    make_uint2(pack2bf(v0, v1), pack2bf(v2, v3));
            }
    }
    // wave-private rows + in-order DS pipe: no barrier needed

    // ====== layer 2: h2^T = dW1^T @ h1^T, both mt merged ======
    {
        short8 a2[2][2];
        #pragma unroll
        for (int mt = 0; mt < 2; ++mt)
            #pragma unroll
            for (int cch = 0; cch < 2; ++cch)
                a2[mt][cch] = *(const short8*)(hb + (mt * 16 + cl) * HP + cch * 32 + q * 8);
        floatx4 acc[2][4];
        #pragma unroll
        for (int mt = 0; mt < 2; ++mt)
            #pragma unroll
            for (int g = 0; g < 4; ++g) acc[mt][g] = (floatx4)0.0f;
        #pragma unroll
        for (int cch = 0; cch < 2; ++cch)
            #pragma unroll
            for (int g = 0; g < 4; ++g) {
                short8 bf = ldfrag(wsfrag, NF_DW0 + cch * 4 + g, lane);
                acc[0][g] = __builtin_amdgcn_mfma_f32_16x16x32_bf16(bf, a2[0][cch], acc[0][g], 0, 0, 0);
                acc[1][g] = __builtin_amdgcn_mfma_f32_16x16x32_bf16(bf, a2[1][cch], acc[1][g], 0, 0, 0);
            }
        #pragma unroll
        for (int mt = 0; mt < 2; ++mt)
            #pragma unroll
            for (int g = 0; g < 4; ++g) {
                floatx4 bias = *(const floatx4*)(db1 + g * 16 + 4 * q);
                float v0 = fmaxf(acc[mt][g][0] + bias[0], 0.0f);
                float v1 = fmaxf(acc[mt][g][1] + bias[1], 0.0f);
                float v2 = fmaxf(acc[mt][g][2] + bias[2], 0.0f);
                float v3 = fmaxf(acc[mt][g][3] + bias[3], 0.0f);
                *(uint2*)(hb + (size_t)(mt * 16 + cl) * HP + g * 16 + 4 * q) =
                    make_uint2(pack2bf(v0, v1), pack2bf(v2, v3));
            }
    }

    // ====== density: p^T = softmax(dbW^T @ h2^T + dbB) + interp ======
    // thread holds logits for grid dims 4q+r of batch row cl
    {
        float tden[2];
        #pragma unroll
        for (int mt = 0; mt < 2; ++mt)
            tden[mt] = dosage[rowbase + mt * 16 + cl];
        short8 af[2][2];
        #pragma unroll
        for (int mt = 0; mt < 2; ++mt)
            #pragma unroll
            for (int cch = 0; cch < 2; ++cch)
                af[mt][cch] = *(const short8*)(hb + (mt * 16 + cl) * HP + cch * 32 + q * 8);
        floatx4 accd[2];
        accd[0] = (floatx4)0.0f; accd[1] = (floatx4)0.0f;
        #pragma unroll
        for (int cch = 0; cch < 2; ++cch) {
            short8 bf = ldfrag(wsfrag, NF_DW0 + NF_DW1 + cch, lane);
            #pragma unroll
            for (int mt = 0; mt < 2; ++mt)
                accd[mt] = __builtin_amdgcn_mfma_f32_16x16x32_bf16(bf, af[mt][cch], accd[mt], 0, 0, 0);
        }
        #pragma unroll
        for (int mt = 0; mt < 2; ++mt) {
            floatx4 ev;
            float sp = 0.0f;
            #pragma unroll
            for (int r = 0; r < 4; ++r) {
                const int gd = 4 * q + r;
                float e = (gd <= G) ? __expf(accd[mt][r] + dbB[gd]) : 0.0f;
                ev[r] = e;
                sp += e;
            }
            float s = sp;
            s += __shfl_xor(s, 16); s += __shfl_xor(s, 32);   // sum over grid dims
            *(floatx4*)(&pbuf[wave][cl][4 * q]) = ev;         // exchange across q
            const float tt = tden[mt];
            const float tB = tt * (float)G;
            const float U  = ceilf(tB);
            const float inter = 1.0f - (U - tB);
            int Ui = (int)U; int Li = Ui - 1; if (Li < 0) Li = 0;
            const float pL = pbuf[wave][cl][Li];
            const float pU = pbuf[wave][cl][Ui];
            if (q == 0)
                outg[rowbase + mt * 16 + cl] = (pL + (pU - pL) * inter) / s;
        }
    }

    // ====== heads: h0^T = W0^T @ h2^T on the wave's own sorted tiles ======
    // (no barrier: perm/tbufs/bks and hbuf were written by THIS wave)
    {
        short8 ag[2][2];
        int    prow[2], bkme[2], blo[2], bhi[2];
        float  tme[2];
        #pragma unroll
        for (int mt = 0; mt < 2; ++mt) {
            const int base = mt * 16;                // sorted 16-row tile in wave
            prow[mt] = perm[wave][base + cl];        // thread's batch row = cl
            ag[mt][0] = *(const short8*)(hb + prow[mt] * HP + q * 8);
            ag[mt][1] = *(const short8*)(hb + prow[mt] * HP + 32 + q * 8);
            tme[mt]  = tbufs[wave][base + cl];
            bkme[mt] = bks[wave][base + cl];
            blo[mt]  = bks[wave][base];
            bhi[mt]  = bks[wave][base + 15];         // contiguous bucket range
        }
        #pragma unroll
        for (int mt = 0; mt < 2; ++mt) {
            float qp = 0.0f;
            #pragma unroll 1
            for (int h = blo[mt]; h <= bhi[mt]; ++h) {
                floatx4 acch[4];
                #pragma unroll
                for (int g = 0; g < 4; ++g) acch[g] = (floatx4)0.0f;
                #pragma unroll
                for (int cch = 0; cch < 2; ++cch)
                    #pragma unroll
                    for (int g = 0; g < 4; ++g) {
                        short8 bf = ldfrag(wsfrag, NF_LIN + h * 8 + cch * 4 + g, lane);
                        acch[g] = __builtin_amdgcn_mfma_f32_16x16x32_bf16(bf, ag[mt][cch], acch[g], 0, 0, 0);
                    }
                if (bkme[mt] == h) { // exec-masked: total epilogue ~= one pass
                    #pragma unroll
                    for (int g = 0; g < 4; ++g) {
                        const int off = h * H + g * 16 + 4 * q;
                        floatx4 tw0v = *(const floatx4*)(tw0 + off);
                        floatx4 b0v  = *(const floatx4*)(b0  + off);
                        floatx4 w1v  = *(const floatx4*)(W1  + off);
                        #pragma unroll
                        for (int r = 0; r < 4; ++r)
                            qp += fmaxf(acch[g][r] + tme[mt] * tw0v[r] + b0v[r], 0.0f) * w1v[r];
                    }
                }
            }
            qp += __shfl_xor(qp, 16); qp += __shfl_xor(qp, 32);   // sum over hid
            if (q == 0)
                qbufs[wave][prow[mt]] = qp + tme[mt] * tw1[bkme[mt]] + b1[bkme[mt]];
        }
    }

    // coalesced Q store of the wave's 32 rows (same-wave in-order DS)
    if (lane < 8) {
        floatx4 v = *(const floatx4*)(&qbufs[wave][lane * 4]);
        *(floatx4*)(outq + rowbase + lane * 4) = v;
    }
}

extern "C" void kernel_launch(void* const* d_in, const int* in_sizes, int n_in,
                              void* d_out, int out_size, void* d_ws, size_t ws_size,
                              hipStream_t stream) {
    const float* dosage = (const float*)d_in[0];
    const float* x      = (const float*)d_in[1];
    const float* dW0    = (const float*)d_in[2];
    const float* db0    = (const float*)d_in[3];
    const float* dW1    = (const float*)d_in[4];
    const float* db1    = (const float*)d_in[5];
    const float* dbW    = (const float*)d_in[6];
    const float* dbB    = (const float*)d_in[7];
    const float* W0     = (const float*)d_in[8];
    const float* tw0    = (const float*)d_in[9];
    const float* b0     = (const float*)d_in[10];
    const float* W1     = (const float*)d_in[11];
    const float* tw1    = (const float*)d_in[12];
    const float* b1     = (const float*)d_in[13];

    const int Btot = in_sizes[0];
    float* outg = (float*)d_out;
    float* outq = outg + Btot;
    unsigned short* ws = (unsigned short*)d_ws;

    pack_kernel<<<NF_TOT, 64, 0, stream>>>(dW0, dW1, dbW, W0, ws);
    drnet_mfma<<<Btot / MWG, 256, 0, stream>>>(dosage, x, db0, db1, dbB,
                                               tw0, b0, W1, tw1, b1,
                                               ws, outg, outq);
}

// Round 9
// 211.227 us; speedup vs baseline: 1.2509x; 1.0793x over previous
//
#include <hip/hip_runtime.h>

typedef __attribute__((ext_vector_type(8))) short  short8;
typedef __attribute__((ext_vector_type(4))) float  floatx4;
typedef __attribute__((ext_vector_type(4))) int    intx4;

constexpr int DIN = 100;
constexpr int H   = 64;
constexpr int G   = 10;
constexpr int NH  = 5;
constexpr int MWG = 128;                 // rows per block (4 waves x 32 rows)
constexpr int HP  = 72;                  // hbuf pitch in halfwords: 144B rows, 16B-aligned
constexpr int PBP = 20;                  // pbuf pitch (floats): 16 payload + 4 pad

// fragment counts in ws: dW0 (K=128 padded) 16; dW1 8; dbW 2; W0 5h*8=40
constexpr int NF_DW0 = 16, NF_DW1 = 8, NF_DBW = 2;
constexpr int NF_LIN = NF_DW0 + NF_DW1 + NF_DBW;     // 26
constexpr int NF_TOT = NF_LIN + 40;                  // 66

__device__ __forceinline__ unsigned short f2bf_rne(float f) {
    union { float f; unsigned u; } v{f};
    unsigned r = v.u + 0x7FFF + ((v.u >> 16) & 1);   // RNE
    return (unsigned short)(r >> 16);
}

// round-half-up pack of 8 floats -> short8 (bf16)
__device__ __forceinline__ short8 pack8(const float* f) {
    intx4 p;
    #pragma unroll
    for (int j = 0; j < 4; ++j) {
        unsigned a = __float_as_uint(f[2 * j])     + 0x8000u;
        unsigned b = __float_as_uint(f[2 * j + 1]) + 0x8000u;
        p[j] = (int)((b & 0xFFFF0000u) | (a >> 16));
    }
    union { intx4 i; short8 s; } u; u.i = p;
    return u.s;
}

// round-half-up pack of 2 floats -> one dword of 2 bf16 (same rounding as above)
__device__ __forceinline__ unsigned pack2bf(float a, float b) {
    unsigned ua = __float_as_uint(a) + 0x8000u;
    unsigned ub = __float_as_uint(b) + 0x8000u;
    return (ua >> 16) | (ub & 0xFFFF0000u);
}

__device__ __forceinline__ short8 ldfrag(const unsigned short* __restrict__ ws,
                                         int f, int lane) {
    return *(const short8*)(ws + (size_t)(f * 64 + lane) * 8);
}

// ---- pre-kernel: pack all weights as bf16 MFMA fragments into ws ----
// Layout note: lane holds W[k = (lane>>4)*8 + j][n = lane&15]. This is
// simultaneously the B-fragment of W and the A-fragment of W^T — the main
// kernel uses them as A-operands to compute transposed outputs h^T.
__global__ __launch_bounds__(64) void pack_kernel(
    const float* __restrict__ dW0, const float* __restrict__ dW1,
    const float* __restrict__ dbW, const float* __restrict__ W0,
    unsigned short* __restrict__ ws)
{
    const int f = blockIdx.x;            // fragment id 0..65
    const int lane = threadIdx.x;
    const int q = lane >> 4, cl = lane & 15;
    float v[8];
    if (f < NF_DW0) {                    // dW0: K padded 100->128 with zeros
        int c = f >> 2, g = f & 3;
        #pragma unroll
        for (int j = 0; j < 8; ++j) {
            int k = c * 32 + q * 8 + j, n = g * 16 + cl;
            v[j] = (k < DIN) ? dW0[k * H + n] : 0.0f;
        }
    } else if (f < NF_DW0 + NF_DW1) {    // dW1: K=64
        int r = f - NF_DW0; int c = r >> 2, g = r & 3;
        #pragma unroll
        for (int j = 0; j < 8; ++j) {
            int k = c * 32 + q * 8 + j, n = g * 16 + cl;
            v[j] = dW1[k * H + n];
        }
    } else if (f < NF_LIN) {             // dbW: K=64, N=11 padded to 16
        int c = f - (NF_DW0 + NF_DW1);
        #pragma unroll
        for (int j = 0; j < 8; ++j) {
            int k = c * 32 + q * 8 + j, n = cl;
            v[j] = (n <= G) ? dbW[k * (G + 1) + n] : 0.0f;
        }
    } else {                             // W0: 5 heads, K=64
        int r = f - NF_LIN; int h = r >> 3; r &= 7; int c = r >> 2, g = r & 3;
        #pragma unroll
        for (int j = 0; j < 8; ++j) {
            int k = c * 32 + q * 8 + j, n = g * 16 + cl;
            v[j] = W0[(h * H + k) * H + n];
        }
    }
    short8 s;
    #pragma unroll
    for (int j = 0; j < 8; ++j) s[j] = (short)f2bf_rne(v[j]);
    *(short8*)(ws + (size_t)(f * 64 + lane) * 8) = s;
}

// ---- main kernel (operand-swapped MFMAs: D = W^T @ x^T = h^T) ----
// BARRIER-FREE: every phase is wave-private. Each wave owns 32 consecutive
// rows; the dosage-bucket sort is a wave-level ballot counting sort of those
// 32 rows; heads gather from the wave's own hbuf region. Cross-lane LDS
// communication within one wave relies on the in-order per-wave DS pipe.
// __launch_bounds__(256,4): VGPR cap 128 — body needs ~90, so NO SPILLS
// (R8's (256,6) forced 40 VGPRs -> 18 MB scratch writes, +29 us).
__global__ __launch_bounds__(256, 4) void drnet_mfma(
    const float* __restrict__ dosage, const float* __restrict__ x,
    const float* __restrict__ db0, const float* __restrict__ db1,
    const float* __restrict__ dbB,
    const float* __restrict__ tw0, const float* __restrict__ b0,
    const float* __restrict__ W1, const float* __restrict__ tw1,
    const float* __restrict__ b1,
    const unsigned short* __restrict__ wsfrag,
    float* __restrict__ outg, float* __restrict__ outq)
{
    __shared__ unsigned short hbuf[4][32 * HP];  // 18432 B (4608 B per wave)
    __shared__ float          pbuf[4][16][PBP];  //  5120 B: softmax scratch
    __shared__ int            perm[4][32];       //   512 B: sorted pos -> wave row
    __shared__ float          tbufs[4][32];      //   512 B: dosage, sorted order
    __shared__ int            bks[4][32];        //   512 B: bucket, sorted order
    __shared__ float          qbufs[4][32];      //   512 B: Q in wave row order

    const int tid  = threadIdx.x;
    const int wave = tid >> 6, lane = tid & 63;
    const int q = lane >> 4, cl = lane & 15;
    const int rowbase = blockIdx.x * MWG + wave * 32;   // this wave's 32 rows
    unsigned short* hb = hbuf[wave];

    // ======= prefetch this wave's x (liveness: top -> layer 1 only) =======
    floatx4 xv[2][7];
    #pragma unroll
    for (int mt = 0; mt < 2; ++mt) {
        const float* xr = x + (size_t)(rowbase + mt * 16 + cl) * DIN;
        #pragma unroll
        for (int cch = 0; cch < 3; ++cch) {
            xv[mt][2 * cch]     = *(const floatx4*)(xr + cch * 32 + q * 8);
            xv[mt][2 * cch + 1] = *(const floatx4*)(xr + cch * 32 + q * 8 + 4);
        }
        xv[mt][6] = (q == 0) ? *(const floatx4*)(xr + 96) : (floatx4)0.0f;
    }

    // ======= wave-private ballot counting sort of the wave's 32 rows =======
    // lanes 32-63 mirror lanes 0-31 (row = lane&31); ballots dedup'd by
    // truncating to the low 32 bits. Register-only: no atomics, no barriers.
    {
        const int row = lane & 31;
        const float tl = dosage[rowbase + row];
        int bk = (int)floorf(tl * (float)NH);
        bk = min(max(bk, 0), NH - 1);
        const unsigned m0 = (unsigned)__ballot(bk == 0);
        const unsigned m1 = (unsigned)__ballot(bk == 1);
        const unsigned m2 = (unsigned)__ballot(bk == 2);
        const unsigned m3 = (unsigned)__ballot(bk == 3);
        const unsigned m4 = (unsigned)__ballot(bk == 4);
        int base = 0;
        base += (bk > 0) ? __popc(m0) : 0;
        base += (bk > 1) ? __popc(m1) : 0;
        base += (bk > 2) ? __popc(m2) : 0;
        base += (bk > 3) ? __popc(m3) : 0;
        const unsigned mymask = (bk == 0) ? m0 : (bk == 1) ? m1 :
                                (bk == 2) ? m2 : (bk == 3) ? m3 : m4;
        const int pos = base + __popc(mymask & ((1u << row) - 1u));
        if (lane < 32) {                 // one writer per row
            perm[wave][pos]  = row;
            tbufs[wave][pos] = tl;
            bks[wave][pos]   = bk;
        }
    }

    // ====== layer 1: h1^T = dW0^T @ x^T, both mt merged (8 acc chains) ======
    {
        short8 a1[2][4];
        #pragma unroll
        for (int mt = 0; mt < 2; ++mt)
            #pragma unroll
            for (int cch = 0; cch < 4; ++cch) {
                float f[8];
                if (cch < 3) {
                    #pragma unroll
                    for (int j = 0; j < 4; ++j) {
                        f[j]     = xv[mt][2 * cch][j];
                        f[4 + j] = xv[mt][2 * cch + 1][j];
                    }
                } else {
                    #pragma unroll
                    for (int j = 0; j < 4; ++j) {
                        f[j]     = xv[mt][6][j];
                        f[4 + j] = 0.0f;
                    }
                }
                a1[mt][cch] = pack8(f);
            }
        floatx4 acc[2][4];
        #pragma unroll
        for (int mt = 0; mt < 2; ++mt)
            #pragma unroll
            for (int g = 0; g < 4; ++g) acc[mt][g] = (floatx4)0.0f;
        #pragma unroll
        for (int cch = 0; cch < 4; ++cch)
            #pragma unroll
            for (int g = 0; g < 4; ++g) {
                short8 bf = ldfrag(wsfrag, cch * 4 + g, lane);  // shared by both mt
                acc[0][g] = __builtin_amdgcn_mfma_f32_16x16x32_bf16(bf, a1[0][cch], acc[0][g], 0, 0, 0);
                acc[1][g] = __builtin_amdgcn_mfma_f32_16x16x32_bf16(bf, a1[1][cch], acc[1][g], 0, 0, 0);
            }
        #pragma unroll
        for (int mt = 0; mt < 2; ++mt)
            #pragma unroll
            for (int g = 0; g < 4; ++g) {
                floatx4 bias = *(const floatx4*)(db0 + g * 16 + 4 * q);
                float v0 = fmaxf(acc[mt][g][0] + bias[0], 0.0f);
                float v1 = fmaxf(acc[mt][g][1] + bias[1], 0.0f);
                float v2 = fmaxf(acc[mt][g][2] + bias[2], 0.0f);
                float v3 = fmaxf(acc[mt][g][3] + bias[3], 0.0f);
                *(uint2*)(hb + (size_t)(mt * 16 + cl) * HP + g * 16 + 4 * q) =
                    make_uint2(pack2bf(v0, v1), pack2bf(v2, v3));
            }
    }
    // wave-private rows + in-order DS pipe: no barrier needed

    // ====== layer 2: h2^T = dW1^T @ h1^T, both mt merged ======
    {
        short8 a2[2][2];
        #pragma unroll
        for (int mt = 0; mt < 2; ++mt)
            #pragma unroll
            for (int cch = 0; cch < 2; ++cch)
                a2[mt][cch] = *(const short8*)(hb + (mt * 16 + cl) * HP + cch * 32 + q * 8);
        floatx4 acc[2][4];
        #pragma unroll
        for (int mt = 0; mt < 2; ++mt)
            #pragma unroll
            for (int g = 0; g < 4; ++g) acc[mt][g] = (floatx4)0.0f;
        #pragma unroll
        for (int cch = 0; cch < 2; ++cch)
            #pragma unroll
            for (int g = 0; g < 4; ++g) {
                short8 bf = ldfrag(wsfrag, NF_DW0 + cch * 4 + g, lane);
                acc[0][g] = __builtin_amdgcn_mfma_f32_16x16x32_bf16(bf, a2[0][cch], acc[0][g], 0, 0, 0);
                acc[1][g] = __builtin_amdgcn_mfma_f32_16x16x32_bf16(bf, a2[1][cch], acc[1][g], 0, 0, 0);
            }
        #pragma unroll
        for (int mt = 0; mt < 2; ++mt)
            #pragma unroll
            for (int g = 0; g < 4; ++g) {
                floatx4 bias = *(const floatx4*)(db1 + g * 16 + 4 * q);
                float v0 = fmaxf(acc[mt][g][0] + bias[0], 0.0f);
                float v1 = fmaxf(acc[mt][g][1] + bias[1], 0.0f);
                float v2 = fmaxf(acc[mt][g][2] + bias[2], 0.0f);
                float v3 = fmaxf(acc[mt][g][3] + bias[3], 0.0f);
                *(uint2*)(hb + (size_t)(mt * 16 + cl) * HP + g * 16 + 4 * q) =
                    make_uint2(pack2bf(v0, v1), pack2bf(v2, v3));
            }
    }

    // ====== density: p^T = softmax(dbW^T @ h2^T + dbB) + interp ======
    // thread holds logits for grid dims 4q+r of batch row cl
    {
        float tden[2];
        #pragma unroll
        for (int mt = 0; mt < 2; ++mt)
            tden[mt] = dosage[rowbase + mt * 16 + cl];
        short8 af[2][2];
        #pragma unroll
        for (int mt = 0; mt < 2; ++mt)
            #pragma unroll
            for (int cch = 0; cch < 2; ++cch)
                af[mt][cch] = *(const short8*)(hb + (mt * 16 + cl) * HP + cch * 32 + q * 8);
        floatx4 accd[2];
        accd[0] = (floatx4)0.0f; accd[1] = (floatx4)0.0f;
        #pragma unroll
        for (int cch = 0; cch < 2; ++cch) {
            short8 bf = ldfrag(wsfrag, NF_DW0 + NF_DW1 + cch, lane);
            #pragma unroll
            for (int mt = 0; mt < 2; ++mt)
                accd[mt] = __builtin_amdgcn_mfma_f32_16x16x32_bf16(bf, af[mt][cch], accd[mt], 0, 0, 0);
        }
        #pragma unroll
        for (int mt = 0; mt < 2; ++mt) {
            floatx4 ev;
            float sp = 0.0f;
            #pragma unroll
            for (int r = 0; r < 4; ++r) {
                const int gd = 4 * q + r;
                float e = (gd <= G) ? __expf(accd[mt][r] + dbB[gd]) : 0.0f;
                ev[r] = e;
                sp += e;
            }
            float s = sp;
            s += __shfl_xor(s, 16); s += __shfl_xor(s, 32);   // sum over grid dims
            *(floatx4*)(&pbuf[wave][cl][4 * q]) = ev;         // exchange across q
            const float tt = tden[mt];
            const float tB = tt * (float)G;
            const float U  = ceilf(tB);
            const float inter = 1.0f - (U - tB);
            int Ui = (int)U; int Li = Ui - 1; if (Li < 0) Li = 0;
            const float pL = pbuf[wave][cl][Li];
            const float pU = pbuf[wave][cl][Ui];
            if (q == 0)
                outg[rowbase + mt * 16 + cl] = (pL + (pU - pL) * inter) / s;
        }
    }

    // ====== heads: h0^T = W0^T @ h2^T on the wave's own sorted tiles ======
    // (no barrier: perm/tbufs/bks and hbuf were written by THIS wave)
    {
        short8 ag[2][2];
        int    prow[2], bkme[2], blo[2], bhi[2];
        float  tme[2];
        #pragma unroll
        for (int mt = 0; mt < 2; ++mt) {
            const int base = mt * 16;                // sorted 16-row tile in wave
            prow[mt] = perm[wave][base + cl];        // thread's batch row = cl
            ag[mt][0] = *(const short8*)(hb + prow[mt] * HP + q * 8);
            ag[mt][1] = *(const short8*)(hb + prow[mt] * HP + 32 + q * 8);
            tme[mt]  = tbufs[wave][base + cl];
            bkme[mt] = bks[wave][base + cl];
            blo[mt]  = bks[wave][base];
            bhi[mt]  = bks[wave][base + 15];         // contiguous bucket range
        }
        #pragma unroll
        for (int mt = 0; mt < 2; ++mt) {
            float qp = 0.0f;
            #pragma unroll 1
            for (int h = blo[mt]; h <= bhi[mt]; ++h) {
                floatx4 acch[4];
                #pragma unroll
                for (int g = 0; g < 4; ++g) acch[g] = (floatx4)0.0f;
                #pragma unroll
                for (int cch = 0; cch < 2; ++cch)
                    #pragma unroll
                    for (int g = 0; g < 4; ++g) {
                        short8 bf = ldfrag(wsfrag, NF_LIN + h * 8 + cch * 4 + g, lane);
                        acch[g] = __builtin_amdgcn_mfma_f32_16x16x32_bf16(bf, ag[mt][cch], acch[g], 0, 0, 0);
                    }
                if (bkme[mt] == h) { // exec-masked: total epilogue ~= one pass
                    #pragma unroll
                    for (int g = 0; g < 4; ++g) {
                        const int off = h * H + g * 16 + 4 * q;
                        floatx4 tw0v = *(const floatx4*)(tw0 + off);
                        floatx4 b0v  = *(const floatx4*)(b0  + off);
                        floatx4 w1v  = *(const floatx4*)(W1  + off);
                        #pragma unroll
                        for (int r = 0; r < 4; ++r)
                            qp += fmaxf(acch[g][r] + tme[mt] * tw0v[r] + b0v[r], 0.0f) * w1v[r];
                    }
                }
            }
            qp += __shfl_xor(qp, 16); qp += __shfl_xor(qp, 32);   // sum over hid
            if (q == 0)
                qbufs[wave][prow[mt]] = qp + tme[mt] * tw1[bkme[mt]] + b1[bkme[mt]];
        }
    }

    // coalesced Q store of the wave's 32 rows (same-wave in-order DS)
    if (lane < 8) {
        floatx4 v = *(const floatx4*)(&qbufs[wave][lane * 4]);
        *(floatx4*)(outq + rowbase + lane * 4) = v;
    }
}

extern "C" void kernel_launch(void* const* d_in, const int* in_sizes, int n_in,
                              void* d_out, int out_size, void* d_ws, size_t ws_size,
                              hipStream_t stream) {
    const float* dosage = (const float*)d_in[0];
    const float* x      = (const float*)d_in[1];
    const float* dW0    = (const float*)d_in[2];
    const float* db0    = (const float*)d_in[3];
    const float* dW1    = (const float*)d_in[4];
    const float* db1    = (const float*)d_in[5];
    const float* dbW    = (const float*)d_in[6];
    const float* dbB    = (const float*)d_in[7];
    const float* W0     = (const float*)d_in[8];
    const float* tw0    = (const float*)d_in[9];
    const float* b0     = (const float*)d_in[10];
    const float* W1     = (const float*)d_in[11];
    const float* tw1    = (const float*)d_in[12];
    const float* b1     = (const float*)d_in[13];

    const int Btot = in_sizes[0];
    float* outg = (float*)d_out;
    float* outq = outg + Btot;
    unsigned short* ws = (unsigned short*)d_ws;

    pack_kernel<<<NF_TOT, 64, 0, stream>>>(dW0, dW1, dbW, W0, ws);
    drnet_mfma<<<Btot / MWG, 256, 0, stream>>>(dosage, x, db0, db1, dbB,
                                               tw0, b0, W1, tw1, b1,
                                               ws, outg, outq);
}

// Round 10
// 198.016 us; speedup vs baseline: 1.3344x; 1.0667x over previous
//
#include <hip/hip_runtime.h>

typedef __attribute__((ext_vector_type(8))) short  short8;
typedef __attribute__((ext_vector_type(4))) float  floatx4;
typedef __attribute__((ext_vector_type(4))) int    intx4;

constexpr int DIN = 100;
constexpr int H   = 64;
constexpr int G   = 10;
constexpr int NH  = 5;
constexpr int MWG = 128;                 // rows per block (4 waves x 32 rows)
constexpr int HP  = 72;                  // hbuf pitch in halfwords: 144B rows, 16B-aligned
constexpr int PBP = 20;                  // pbuf pitch (floats): 16 payload + 4 pad

// fragment counts in ws: dW0 (K=128 padded) 16; dW1 8; dbW 2; W0 5h*8=40
constexpr int NF_DW0 = 16, NF_DW1 = 8, NF_DBW = 2;
constexpr int NF_LIN = NF_DW0 + NF_DW1 + NF_DBW;     // 26 (staged in LDS)
constexpr int NF_TOT = NF_LIN + 40;                  // 66

__device__ __forceinline__ unsigned short f2bf_rne(float f) {
    union { float f; unsigned u; } v{f};
    unsigned r = v.u + 0x7FFF + ((v.u >> 16) & 1);   // RNE
    return (unsigned short)(r >> 16);
}

// round-half-up pack of 8 floats -> short8 (bf16)
__device__ __forceinline__ short8 pack8(const float* f) {
    intx4 p;
    #pragma unroll
    for (int j = 0; j < 4; ++j) {
        unsigned a = __float_as_uint(f[2 * j])     + 0x8000u;
        unsigned b = __float_as_uint(f[2 * j + 1]) + 0x8000u;
        p[j] = (int)((b & 0xFFFF0000u) | (a >> 16));
    }
    union { intx4 i; short8 s; } u; u.i = p;
    return u.s;
}

// round-half-up pack of 2 floats -> one dword of 2 bf16 (same rounding as above)
__device__ __forceinline__ unsigned pack2bf(float a, float b) {
    unsigned ua = __float_as_uint(a) + 0x8000u;
    unsigned ub = __float_as_uint(b) + 0x8000u;
    return (ua >> 16) | (ub & 0xFFFF0000u);
}

__device__ __forceinline__ short8 ldfrag(const unsigned short* __restrict__ ws,
                                         int f, int lane) {
    return *(const short8*)(ws + (size_t)(f * 64 + lane) * 8);
}

// lgkm-only barrier: does NOT drain vmcnt, so in-flight global loads and
// global_load_lds staging survive it. All cross-wave deps here are LDS.
__device__ __forceinline__ void bar_lgkm() {
    asm volatile("s_waitcnt lgkmcnt(0)" ::: "memory");
    __builtin_amdgcn_s_barrier();
    asm volatile("" ::: "memory");
}

// full barrier incl. vmcnt drain (used once: staging -> layer1)
__device__ __forceinline__ void bar_vm() {
    asm volatile("s_waitcnt vmcnt(0) lgkmcnt(0)" ::: "memory");
    __builtin_amdgcn_s_barrier();
    asm volatile("" ::: "memory");
}

// ---- pre-kernel: pack all weights as bf16 MFMA fragments into ws ----
// Layout note: lane holds W[k = (lane>>4)*8 + j][n = lane&15]. This is
// simultaneously the B-fragment of W and the A-fragment of W^T — the main
// kernel uses them as A-operands to compute transposed outputs h^T.
__global__ __launch_bounds__(64) void pack_kernel(
    const float* __restrict__ dW0, const float* __restrict__ dW1,
    const float* __restrict__ dbW, const float* __restrict__ W0,
    unsigned short* __restrict__ ws)
{
    const int f = blockIdx.x;            // fragment id 0..65
    const int lane = threadIdx.x;
    const int q = lane >> 4, cl = lane & 15;
    float v[8];
    if (f < NF_DW0) {                    // dW0: K padded 100->128 with zeros
        int c = f >> 2, g = f & 3;
        #pragma unroll
        for (int j = 0; j < 8; ++j) {
            int k = c * 32 + q * 8 + j, n = g * 16 + cl;
            v[j] = (k < DIN) ? dW0[k * H + n] : 0.0f;
        }
    } else if (f < NF_DW0 + NF_DW1) {    // dW1: K=64
        int r = f - NF_DW0; int c = r >> 2, g = r & 3;
        #pragma unroll
        for (int j = 0; j < 8; ++j) {
            int k = c * 32 + q * 8 + j, n = g * 16 + cl;
            v[j] = dW1[k * H + n];
        }
    } else if (f < NF_LIN) {             // dbW: K=64, N=11 padded to 16
        int c = f - (NF_DW0 + NF_DW1);
        #pragma unroll
        for (int j = 0; j < 8; ++j) {
            int k = c * 32 + q * 8 + j, n = cl;
            v[j] = (n <= G) ? dbW[k * (G + 1) + n] : 0.0f;
        }
    } else {                             // W0: 5 heads, K=64
        int r = f - NF_LIN; int h = r >> 3; r &= 7; int c = r >> 2, g = r & 3;
        #pragma unroll
        for (int j = 0; j < 8; ++j) {
            int k = c * 32 + q * 8 + j, n = g * 16 + cl;
            v[j] = W0[(h * H + k) * H + n];
        }
    }
    short8 s;
    #pragma unroll
    for (int j = 0; j < 8; ++j) s[j] = (short)f2bf_rne(v[j]);
    *(short8*)(ws + (size_t)(f * 64 + lane) * 8) = s;
}

// ---- main kernel (operand-swapped MFMAs: D = W^T @ x^T = h^T) ----
// NEW: the 26 linear-phase weight fragments (dW0/dW1/dbW, 26KB) are staged
// into LDS once per block via global_load_lds (lane x 16B layout matches the
// intrinsic exactly); layers+density then ds_read instead of each wave
// streaming 26KB from L2 through the 32KB L1. Staging + x-prefetch latency
// hide under the block-wide counting sort (lgkm-only barriers keep them in
// flight); one vmcnt(0)+barrier before layer 1.
__global__ __launch_bounds__(256, 3) void drnet_mfma(
    const float* __restrict__ dosage, const float* __restrict__ x,
    const float* __restrict__ db0, const float* __restrict__ db1,
    const float* __restrict__ dbB,
    const float* __restrict__ tw0, const float* __restrict__ b0,
    const float* __restrict__ W1, const float* __restrict__ tw1,
    const float* __restrict__ b1,
    const unsigned short* __restrict__ wsfrag,
    float* __restrict__ outg, float* __restrict__ outq)
{
    __shared__ unsigned short hbuf[MWG * HP];        // 18432 B
    __shared__ unsigned short wstage[NF_LIN * 512];  // 26624 B: staged fragments
    __shared__ float          pbuf[4][16][PBP];      //  5120 B: softmax scratch
    __shared__ int            perm[MWG];             // sorted pos -> row-in-block
    __shared__ float          tbuf[MWG];             // dosage in sorted order
    __shared__ unsigned char  bkbuf[MWG];            // bucket in sorted order
    __shared__ float          qbuf[MWG];             // Q in original row order
    __shared__ int            hist[NH];
    __shared__ int            offs[NH];

    const int tid  = threadIdx.x;
    const int wave = tid >> 6, lane = tid & 63;
    const int q = lane >> 4, cl = lane & 15;
    const int rowbase = blockIdx.x * MWG + wave * 32;   // this wave's 32 rows
    unsigned short* hb = hbuf + wave * 32 * HP;

    // frag read from LDS stage (lane i holds bytes [16i,16i+16) of frag f)
    auto ldsfrag = [&](int f) -> short8 {
        return *(const short8*)(wstage + f * 512 + lane * 8);
    };

    // ======= phase -1a: issue LDS staging of the 26 linear fragments =======
    // global_load_lds: LDS dest = uniform base + lane*16 — exactly our layout.
    #pragma unroll
    for (int f0 = 0; f0 < 28; f0 += 4) {             // waves round-robin frags
        const int f = f0 + wave;
        if (f < NF_LIN) {
            __builtin_amdgcn_global_load_lds(
                (const __attribute__((address_space(1))) void*)
                    (wsfrag + (size_t)(f * 64 + lane) * 8),
                (__attribute__((address_space(3))) void*)
                    (wstage + f * 512),
                16, 0, 0);
        }
    }

    // ======= phase -1b: issue this wave's x / dosage global loads =======
    floatx4 tvs[2];
    #pragma unroll
    for (int mt = 0; mt < 2; ++mt)
        tvs[mt] = *(const floatx4*)(dosage + rowbase + mt * 16 + 4 * q);
    floatx4 xv[2][7];
    #pragma unroll
    for (int mt = 0; mt < 2; ++mt) {
        const float* xr = x + (size_t)(rowbase + mt * 16 + cl) * DIN;
        #pragma unroll
        for (int cch = 0; cch < 3; ++cch) {
            xv[mt][2 * cch]     = *(const floatx4*)(xr + cch * 32 + q * 8);
            xv[mt][2 * cch + 1] = *(const floatx4*)(xr + cch * 32 + q * 8 + 4);
        }
        xv[mt][6] = (q == 0) ? *(const floatx4*)(xr + 96) : (floatx4)0.0f;
    }

    // ================= phase 0: counting sort by dosage bucket =================
    // staging + x loads remain in flight across all of this (lgkm-only bars).
    if (tid < NH) hist[tid] = 0;
    bar_lgkm();
    {
        float t8[2][4];
        int   bk8[2][4];
        #pragma unroll
        for (int mt = 0; mt < 2; ++mt)
            #pragma unroll
            for (int r = 0; r < 4; ++r) {
                float tt = tvs[mt][r];
                t8[mt][r] = tt;
                int bk = (int)floorf(tt * (float)NH);
                bk8[mt][r] = min(max(bk, 0), NH - 1);
            }
        if (cl == 0) {
            #pragma unroll
            for (int mt = 0; mt < 2; ++mt)
                #pragma unroll
                for (int r = 0; r < 4; ++r)
                    atomicAdd(&hist[bk8[mt][r]], 1);
        }
        bar_lgkm();
        if (tid == 0) {
            int a = 0;
            #pragma unroll
            for (int h = 0; h < NH; ++h) { offs[h] = a; a += hist[h]; }
        }
        bar_lgkm();
        if (cl == 0) {
            #pragma unroll
            for (int mt = 0; mt < 2; ++mt)
                #pragma unroll
                for (int r = 0; r < 4; ++r) {
                    const int bk  = bk8[mt][r];
                    const int pos = atomicAdd(&offs[bk], 1);
                    perm[pos]  = wave * 32 + mt * 16 + 4 * q + r;
                    tbuf[pos]  = t8[mt][r];
                    bkbuf[pos] = (unsigned char)bk;
                }
        }
        // perm/tbuf/bkbuf visibility guaranteed by the pre-heads barrier
    }

    // ======= staging + x complete, visible to all waves =======
    bar_vm();

    // ====== layer 1: h1^T = dW0^T @ x^T, both mt merged (8 acc chains) ======
    {
        short8 a1[2][4];
        #pragma unroll
        for (int mt = 0; mt < 2; ++mt)
            #pragma unroll
            for (int cch = 0; cch < 4; ++cch) {
                float f[8];
                if (cch < 3) {
                    #pragma unroll
                    for (int j = 0; j < 4; ++j) {
                        f[j]     = xv[mt][2 * cch][j];
                        f[4 + j] = xv[mt][2 * cch + 1][j];
                    }
                } else {
                    #pragma unroll
                    for (int j = 0; j < 4; ++j) {
                        f[j]     = xv[mt][6][j];
                        f[4 + j] = 0.0f;
                    }
                }
                a1[mt][cch] = pack8(f);
            }
        floatx4 acc[2][4];
        #pragma unroll
        for (int mt = 0; mt < 2; ++mt)
            #pragma unroll
            for (int g = 0; g < 4; ++g) acc[mt][g] = (floatx4)0.0f;
        #pragma unroll
        for (int cch = 0; cch < 4; ++cch)
            #pragma unroll
            for (int g = 0; g < 4; ++g) {
                short8 bf = ldsfrag(cch * 4 + g);        // LDS, shared by both mt
                acc[0][g] = __builtin_amdgcn_mfma_f32_16x16x32_bf16(bf, a1[0][cch], acc[0][g], 0, 0, 0);
                acc[1][g] = __builtin_amdgcn_mfma_f32_16x16x32_bf16(bf, a1[1][cch], acc[1][g], 0, 0, 0);
            }
        #pragma unroll
        for (int mt = 0; mt < 2; ++mt)
            #pragma unroll
            for (int g = 0; g < 4; ++g) {
                floatx4 bias = *(const floatx4*)(db0 + g * 16 + 4 * q);
                float v0 = fmaxf(acc[mt][g][0] + bias[0], 0.0f);
                float v1 = fmaxf(acc[mt][g][1] + bias[1], 0.0f);
                float v2 = fmaxf(acc[mt][g][2] + bias[2], 0.0f);
                float v3 = fmaxf(acc[mt][g][3] + bias[3], 0.0f);
                *(uint2*)(hb + (size_t)(mt * 16 + cl) * HP + g * 16 + 4 * q) =
                    make_uint2(pack2bf(v0, v1), pack2bf(v2, v3));
            }
    }
    // wave-private rows + in-order DS pipe: no barrier needed

    // ====== layer 2: h2^T = dW1^T @ h1^T, both mt merged ======
    {
        short8 a2[2][2];
        #pragma unroll
        for (int mt = 0; mt < 2; ++mt)
            #pragma unroll
            for (int cch = 0; cch < 2; ++cch)
                a2[mt][cch] = *(const short8*)(hb + (mt * 16 + cl) * HP + cch * 32 + q * 8);
        floatx4 acc[2][4];
        #pragma unroll
        for (int mt = 0; mt < 2; ++mt)
            #pragma unroll
            for (int g = 0; g < 4; ++g) acc[mt][g] = (floatx4)0.0f;
        #pragma unroll
        for (int cch = 0; cch < 2; ++cch)
            #pragma unroll
            for (int g = 0; g < 4; ++g) {
                short8 bf = ldsfrag(NF_DW0 + cch * 4 + g);
                acc[0][g] = __builtin_amdgcn_mfma_f32_16x16x32_bf16(bf, a2[0][cch], acc[0][g], 0, 0, 0);
                acc[1][g] = __builtin_amdgcn_mfma_f32_16x16x32_bf16(bf, a2[1][cch], acc[1][g], 0, 0, 0);
            }
        #pragma unroll
        for (int mt = 0; mt < 2; ++mt)
            #pragma unroll
            for (int g = 0; g < 4; ++g) {
                floatx4 bias = *(const floatx4*)(db1 + g * 16 + 4 * q);
                float v0 = fmaxf(acc[mt][g][0] + bias[0], 0.0f);
                float v1 = fmaxf(acc[mt][g][1] + bias[1], 0.0f);
                float v2 = fmaxf(acc[mt][g][2] + bias[2], 0.0f);
                float v3 = fmaxf(acc[mt][g][3] + bias[3], 0.0f);
                *(uint2*)(hb + (size_t)(mt * 16 + cl) * HP + g * 16 + 4 * q) =
                    make_uint2(pack2bf(v0, v1), pack2bf(v2, v3));
            }
    }

    // ====== density: p^T = softmax(dbW^T @ h2^T + dbB) + interp ======
    // thread holds logits for grid dims 4q+r of batch row cl
    {
        float tden[2];
        #pragma unroll
        for (int mt = 0; mt < 2; ++mt)
            tden[mt] = dosage[rowbase + mt * 16 + cl];
        short8 af[2][2];
        #pragma unroll
        for (int mt = 0; mt < 2; ++mt)
            #pragma unroll
            for (int cch = 0; cch < 2; ++cch)
                af[mt][cch] = *(const short8*)(hb + (mt * 16 + cl) * HP + cch * 32 + q * 8);
        floatx4 accd[2];
        accd[0] = (floatx4)0.0f; accd[1] = (floatx4)0.0f;
        #pragma unroll
        for (int cch = 0; cch < 2; ++cch) {
            short8 bf = ldsfrag(NF_DW0 + NF_DW1 + cch);
            #pragma unroll
            for (int mt = 0; mt < 2; ++mt)
                accd[mt] = __builtin_amdgcn_mfma_f32_16x16x32_bf16(bf, af[mt][cch], accd[mt], 0, 0, 0);
        }
        #pragma unroll
        for (int mt = 0; mt < 2; ++mt) {
            floatx4 ev;
            float sp = 0.0f;
            #pragma unroll
            for (int r = 0; r < 4; ++r) {
                const int gd = 4 * q + r;
                float e = (gd <= G) ? __expf(accd[mt][r] + dbB[gd]) : 0.0f;
                ev[r] = e;
                sp += e;
            }
            float s = sp;
            s += __shfl_xor(s, 16); s += __shfl_xor(s, 32);   // sum over grid dims
            *(floatx4*)(&pbuf[wave][cl][4 * q]) = ev;         // exchange across q
            const float tt = tden[mt];
            const float tB = tt * (float)G;
            const float U  = ceilf(tB);
            const float inter = 1.0f - (U - tB);
            int Ui = (int)U; int Li = Ui - 1; if (Li < 0) Li = 0;
            const float pL = pbuf[wave][cl][Li];
            const float pU = pbuf[wave][cl][Ui];
            if (q == 0)
                outg[rowbase + mt * 16 + cl] = (pL + (pU - pL) * inter) / s;
        }
    }

    // ====== heads: h0^T = W0^T @ h2^T on sorted tiles; per-thread bucket ======
    bar_lgkm();      // all h2 in hbuf + perm/tbuf/bkbuf visible (LDS-only)
    {
        short8 ag[2][2];
        int    prow[2], bkme[2], blo[2], bhi[2];
        float  tme[2];
        #pragma unroll
        for (int mt = 0; mt < 2; ++mt) {
            const int base = (wave * 2 + mt) * 16;   // my sorted 16-row tile
            prow[mt] = perm[base + cl];              // thread's batch row = cl
            ag[mt][0] = *(const short8*)(hbuf + prow[mt] * HP + q * 8);
            ag[mt][1] = *(const short8*)(hbuf + prow[mt] * HP + 32 + q * 8);
            tme[mt]  = tbuf[base + cl];
            bkme[mt] = bkbuf[base + cl];
            blo[mt]  = bkbuf[base];
            bhi[mt]  = bkbuf[base + 15];             // contiguous bucket range
        }
        #pragma unroll
        for (int mt = 0; mt < 2; ++mt) {
            float qp = 0.0f;
            #pragma unroll 1
            for (int h = blo[mt]; h <= bhi[mt]; ++h) {
                floatx4 acch[4];
                #pragma unroll
                for (int g = 0; g < 4; ++g) acch[g] = (floatx4)0.0f;
                #pragma unroll
                for (int cch = 0; cch < 2; ++cch)
                    #pragma unroll
                    for (int g = 0; g < 4; ++g) {
                        short8 bf = ldfrag(wsfrag, NF_LIN + h * 8 + cch * 4 + g, lane);
                        acch[g] = __builtin_amdgcn_mfma_f32_16x16x32_bf16(bf, ag[mt][cch], acch[g], 0, 0, 0);
                    }
                if (bkme[mt] == h) { // exec-masked: total epilogue ~= one pass
                    #pragma unroll
                    for (int g = 0; g < 4; ++g) {
                        const int off = h * H + g * 16 + 4 * q;
                        floatx4 tw0v = *(const floatx4*)(tw0 + off);
                        floatx4 b0v  = *(const floatx4*)(b0  + off);
                        floatx4 w1v  = *(const floatx4*)(W1  + off);
                        #pragma unroll
                        for (int r = 0; r < 4; ++r)
                            qp += fmaxf(acch[g][r] + tme[mt] * tw0v[r] + b0v[r], 0.0f) * w1v[r];
                    }
                }
            }
            qp += __shfl_xor(qp, 16); qp += __shfl_xor(qp, 32);   // sum over hid
            if (q == 0)
                qbuf[prow[mt]] = qp + tme[mt] * tw1[bkme[mt]] + b1[bkme[mt]];
        }
    }

    // coalesced Q store (qbuf is in original row order)
    bar_lgkm();
    if (tid < MWG / 4) {
        floatx4 v = *(const floatx4*)(qbuf + tid * 4);
        *(floatx4*)(outq + blockIdx.x * MWG + tid * 4) = v;
    }
}

extern "C" void kernel_launch(void* const* d_in, const int* in_sizes, int n_in,
                              void* d_out, int out_size, void* d_ws, size_t ws_size,
                              hipStream_t stream) {
    const float* dosage = (const float*)d_in[0];
    const float* x      = (const float*)d_in[1];
    const float* dW0    = (const float*)d_in[2];
    const float* db0    = (const float*)d_in[3];
    const float* dW1    = (const float*)d_in[4];
    const float* db1    = (const float*)d_in[5];
    const float* dbW    = (const float*)d_in[6];
    const float* dbB    = (const float*)d_in[7];
    const float* W0     = (const float*)d_in[8];
    const float* tw0    = (const float*)d_in[9];
    const float* b0     = (const float*)d_in[10];
    const float* W1     = (const float*)d_in[11];
    const float* tw1    = (const float*)d_in[12];
    const float* b1     = (const float*)d_in[13];

    const int Btot = in_sizes[0];
    float* outg = (float*)d_out;
    float* outq = outg + Btot;
    unsigned short* ws = (unsigned short*)d_ws;

    pack_kernel<<<NF_TOT, 64, 0, stream>>>(dW0, dW1, dbW, W0, ws);
    drnet_mfma<<<Btot / MWG, 256, 0, stream>>>(dosage, x, db0, db1, dbB,
                                               tw0, b0, W1, tw1, b1,
                                               ws, outg, outq);
}